// Round 1
// baseline (16514.825 us; speedup 1.0000x reference)
//
#include <hip/hip_runtime.h>

typedef unsigned short u16;
typedef unsigned int u32;
typedef unsigned long long u64;
typedef __bf16 bf16x8 __attribute__((ext_vector_type(8)));
typedef float f32x4 __attribute__((ext_vector_type(4)));

__device__ __forceinline__ u16 f2b(float f) {
  unsigned u = __float_as_uint(f);
  return (u16)((u + 0x7fffu + ((u >> 16) & 1u)) >> 16);
}
__device__ __forceinline__ float b2f(u16 h) {
  return __uint_as_float(((unsigned)h) << 16);
}

// LLC-coherent (agent-scope relaxed => sc-bit accesses, no cache-maint fences)
__device__ __forceinline__ void st_b16_llc(u16* p, u16 v) {
  __hip_atomic_store(p, v, __ATOMIC_RELAXED, __HIP_MEMORY_SCOPE_AGENT);
}
__device__ __forceinline__ bf16x8 ld_frag_llc(const u16* p) {
  union { u64 q[2]; bf16x8 v; } u;
  u.q[0] = __hip_atomic_load((const u64*)p,     __ATOMIC_RELAXED, __HIP_MEMORY_SCOPE_AGENT);
  u.q[1] = __hip_atomic_load((const u64*)p + 1, __ATOMIC_RELAXED, __HIP_MEMORY_SCOPE_AGENT);
  return u.v;
}

// ---------------- generic fp32 -> bf16 cast ----------------
__global__ void cast_f32_bf16(const float* __restrict__ in, u16* __restrict__ out, int n) {
  int i = blockIdx.x * 256 + threadIdx.x;
  if (i < n) out[i] = f2b(in[i]);
}

// ---------------- arrive-count device barrier over 256 wgs ----------------
// Per-epoch block of 8 u32 counters (32B, one per bid&7 group of 32 wgs).
// Epoch-indexed (monotone, no reset/ABA). Arrival: tid0 atomicAdd after
// __syncthreads (drains both waves' stores to the coherence point).
// Detection: every wave polls with ONE coalesced 32B load (lanes 0..7) until
// all 8 counters hit 32. Both waves poll, so no trailing __syncthreads hop.
// vs. previous all-scan barrier: poll traffic drops ~30x (256 wgs x 1KB scan
// -> 512 waves x 32B), removing the LLC same-line queueing that was both the
// measured 83 GB/s "HBM" traffic and the ~11us/interval latency.
__device__ __forceinline__ void wg_bar(u32* __restrict__ cnt, int ep,
                                       int bid, int lane, int tid) {
  __syncthreads();
  if (tid == 0)
    __hip_atomic_fetch_add(&cnt[(size_t)ep * 8 + (bid & 7)], 1u,
                           __ATOMIC_RELAXED, __HIP_MEMORY_SCOPE_AGENT);
  const u32* row = cnt + (size_t)ep * 8;
  for (;;) {
    u32 v = 32u;
    if (lane < 8)
      v = __hip_atomic_load(&row[lane], __ATOMIC_RELAXED, __HIP_MEMORY_SCOPE_AGENT);
    if (__all(v >= 32u)) break;
    __builtin_amdgcn_s_sleep(1);
  }
}

// ---------------- tiled bf16 GEMM: C[M,N] = A[M,K] @ B[N,K]^T (fp32 out) ----------------
__global__ __launch_bounds__(256) void gemm_bt(
    const u16* __restrict__ A, const u16* __restrict__ B,
    int M, int N, int K,
    const float* __restrict__ bias, float* __restrict__ Cf)
{
  __shared__ u16 a_sm[128 * 32];
  __shared__ u16 b_sm[128 * 32];
  const int tid = threadIdx.x;
  const int lane = tid & 63;
  const int wid = tid >> 6;
  const int wm = wid >> 1, wn = wid & 1;
  const int m0 = blockIdx.x * 128, n0 = blockIdx.y * 128;
  const int q = lane >> 4, l15 = lane & 15, l3 = lane & 3;

  f32x4 acc[4][4];
  #pragma unroll
  for (int i = 0; i < 4; ++i)
    #pragma unroll
    for (int j = 0; j < 4; ++j) acc[i][j] = (f32x4){0.f, 0.f, 0.f, 0.f};

  for (int kk = 0; kk < K; kk += 32) {
    __syncthreads();
    #pragma unroll
    for (int p = 0; p < 2; ++p) {
      int idx = p * 256 + tid;
      int r = idx >> 2, cch = idx & 3;
      *(uint4*)&a_sm[r * 32 + ((cch ^ (r & 3)) * 8)] =
          *(const uint4*)&A[(size_t)(m0 + r) * K + kk + cch * 8];
      *(uint4*)&b_sm[r * 32 + ((cch ^ (r & 3)) * 8)] =
          *(const uint4*)&B[(size_t)(n0 + r) * K + kk + cch * 8];
    }
    __syncthreads();
    bf16x8 af[4], bfr[4];
    #pragma unroll
    for (int s = 0; s < 4; ++s) {
      int ra = wm * 64 + s * 16 + l15;
      af[s] = *(const bf16x8*)&a_sm[ra * 32 + ((q ^ l3) * 8)];
      int rb = wn * 64 + s * 16 + l15;
      bfr[s] = *(const bf16x8*)&b_sm[rb * 32 + ((q ^ l3) * 8)];
    }
    #pragma unroll
    for (int si = 0; si < 4; ++si)
      #pragma unroll
      for (int sj = 0; sj < 4; ++sj)
        acc[si][sj] = __builtin_amdgcn_mfma_f32_16x16x32_bf16(af[si], bfr[sj], acc[si][sj], 0, 0, 0);
  }

  #pragma unroll
  for (int si = 0; si < 4; ++si)
    #pragma unroll
    for (int sj = 0; sj < 4; ++sj)
      #pragma unroll
      for (int e = 0; e < 4; ++e) {
        int m = m0 + wm * 64 + si * 16 + q * 4 + e;
        int n = n0 + wn * 64 + sj * 16 + l15;
        Cf[(size_t)m * N + n] = acc[si][sj][e] + (bias ? bias[n] : 0.f);
      }
}

// ---------------- fused 2-layer pipelined GRU: 1026 device barriers total ----------------
// 256 wgs x 128 thr. wgs 0-127: layer 0 (n-slice 8 each, K=1024+128 concat [Wh0|Wx0]).
// wgs 128-255: layer 1, one step behind (K=1024+1024 concat [Wh1|Wx1], x-input = h0_t).
// Interval p (t=p>>1, ph=p&1):
//  ph0: L0 phase1(t) reads h0buf[(t-1)&1]; L1 phase1(t-1) reads hb1 + h0buf[(t-1)&1]
//  ph1: L0 phase2(t) -> h0buf[t&1]; L1 phase2(t-1) -> hb1, seq1
// L1 caches the 32 h0 fragments in registers across both phases of a step.
__global__ __launch_bounds__(128, 1) void gru_pipe(
    const u16* __restrict__ Wh0, const u16* __restrict__ Wx0,
    const u16* __restrict__ Wh1, const u16* __restrict__ Wx1,
    const float* __restrict__ bz0, const float* __restrict__ br0, const float* __restrict__ bg0,
    const float* __restrict__ bz1, const float* __restrict__ br1, const float* __restrict__ bg1,
    const u16* __restrict__ xb,                      // [32][512][128] bf16
    const float* __restrict__ h0p,                   // (32,2,1024) fp32
    u16* __restrict__ h0buf,                         // 2 x [32][1024] bf16 rotating
    u16* __restrict__ hb1,                           // [32][1024]
    u16* __restrict__ rh0b, u16* __restrict__ rh1b,  // [32][1024]
    u16* __restrict__ seq1,                          // [32][512][1024] bf16
    float* __restrict__ hid,                         // (32,2,1024) fp32 out
    u32* __restrict__ cnt)                           // [1026][8] epoch counters
{
  __shared__ u16 zr_frag[64 * 512];                  // 64 KB max (L1)
  __shared__ u16 g_frag[64 * 256];                   // 32 KB max

  const int tid = threadIdx.x;
  const int lane = tid & 63;
  const int w = tid >> 6;
  const int bid = blockIdx.x;
  const bool Lyr1 = bid >= 128;
  const int nb = (bid & 127) * 8;
  const int q = lane >> 4, c15 = lane & 15, nl = c15 & 7;
  const int n_own = nb + nl;
  const bool isz = c15 < 8;
  const int brow = w * 16 + c15;                     // A-fragment batch row
  const int KS = Lyr1 ? 64 : 36;                     // K-steps of 32
  const int IN = Lyr1 ? 1024 : 128;
  const u16* Wh = Lyr1 ? Wh1 : Wh0;
  const u16* Wx = Lyr1 ? Wx1 : Wx0;
  const size_t WXG = (size_t)1024 * IN;              // Wx per-gate elems

  // ---- stage concat [Wh | Wx] weights into LDS in MFMA B-frag order ----
  for (int cidx = tid; cidx < KS * 64; cidx += 128) {
    int ks = cidx >> 6, l = cidx & 63;
    int lq = l >> 4, lc = l & 15;
    int row = nb + (lc & 7), gate = (lc < 8) ? 0 : 1;  // z | r
    int k0 = ks * 32 + lq * 8;
    const u16* src = (k0 < 1024)
        ? Wh + (size_t)gate * 1048576 + (size_t)row * 1024 + k0
        : Wx + (size_t)gate * WXG + (size_t)row * IN + (k0 - 1024);
    *(uint4*)&zr_frag[cidx * 8] = *(const uint4*)src;
  }
  for (int gidx = tid; gidx < KS * 32; gidx += 128) {
    int ks = gidx >> 5, s = gidx & 31;
    int lq = s >> 3, r8 = s & 7;
    int row = nb + r8, k0 = ks * 32 + lq * 8;
    const u16* src = (k0 < 1024)
        ? Wh + (size_t)2 * 1048576 + (size_t)row * 1024 + k0
        : Wx + (size_t)2 * WXG + (size_t)row * IN + (k0 - 1024);
    *(uint4*)&g_frag[gidx * 8] = *(const uint4*)src;
  }

  // ---- biases ----
  const float bias1 = isz ? (Lyr1 ? bz1 : bz0)[n_own] : (Lyr1 ? br1 : br0)[n_own];
  const float bias2 = (Lyr1 ? bg1 : bg0)[n_own];

  // ---- init state: z-lanes hold h fp32; publish bf16 ----
  float hreg[4], zreg[4] = {0.f, 0.f, 0.f, 0.f};
  #pragma unroll
  for (int e = 0; e < 4; ++e) {
    int b = w * 16 + q * 4 + e;
    float v = h0p[b * 2048 + (Lyr1 ? 1024 : 0) + n_own];
    hreg[e] = v;
    if (isz)
      st_b16_llc((Lyr1 ? hb1 : h0buf + 32768) + b * 1024 + n_own, f2b(v));
  }
  wg_bar(cnt, 0, bid, lane, tid);

  bf16x8 xf[4];                                      // L0: x frags for step t
  bf16x8 h0f[32];                                    // L1: h0_t frags (regs across phases)

  for (int p = 0; p < 1026; ++p) {
    const int t = p >> 1, ph = p & 1;
    if (!Lyr1) {
      if (t < 512) {
        if (ph == 0) {
          const u16* hp = h0buf + ((t - 1) & 1) * 32768;
          #pragma unroll
          for (int j = 0; j < 4; ++j)
            xf[j] = *(const bf16x8*)&xb[((size_t)brow * 512 + t) * 128 + j * 32 + q * 8];
          f32x4 a0 = {0.f,0.f,0.f,0.f}, a1 = {0.f,0.f,0.f,0.f};
          #pragma unroll
          for (int ks = 0; ks < 32; ++ks) {
            bf16x8 af = ld_frag_llc(hp + (size_t)brow * 1024 + ks * 32 + q * 8);
            a0 = __builtin_amdgcn_mfma_f32_16x16x32_bf16(af, *(const bf16x8*)&zr_frag[ks * 512 + lane * 8], a0, 0, 0, 0);
          }
          #pragma unroll
          for (int ks = 32; ks < 36; ++ks)
            a1 = __builtin_amdgcn_mfma_f32_16x16x32_bf16(xf[ks - 32], *(const bf16x8*)&zr_frag[ks * 512 + lane * 8], a1, 0, 0, 0);
          float hsh[4];
          #pragma unroll
          for (int e = 0; e < 4; ++e) hsh[e] = __shfl_xor(hreg[e], 8);
          #pragma unroll
          for (int e = 0; e < 4; ++e) {
            float pre = a0[e] + a1[e] + bias1;
            float s = 1.f / (1.f + __expf(-pre));
            if (isz) zreg[e] = s;
            else st_b16_llc(&rh0b[(w * 16 + q * 4 + e) * 1024 + n_own], f2b(s * hsh[e]));
          }
        } else {
          f32x4 a0 = {0.f,0.f,0.f,0.f}, a1 = {0.f,0.f,0.f,0.f};
          #pragma unroll
          for (int ks = 0; ks < 32; ++ks) {
            bf16x8 af = ld_frag_llc(rh0b + (size_t)brow * 1024 + ks * 32 + q * 8);
            a0 = __builtin_amdgcn_mfma_f32_16x16x32_bf16(af, *(const bf16x8*)&g_frag[ks * 256 + (q * 8 + nl) * 8], a0, 0, 0, 0);
          }
          #pragma unroll
          for (int ks = 32; ks < 36; ++ks)
            a1 = __builtin_amdgcn_mfma_f32_16x16x32_bf16(xf[ks - 32], *(const bf16x8*)&g_frag[ks * 256 + (q * 8 + nl) * 8], a1, 0, 0, 0);
          if (isz) {
            u16* hout = h0buf + (t & 1) * 32768;
            #pragma unroll
            for (int e = 0; e < 4; ++e) {
              int b = w * 16 + q * 4 + e;
              float pre = a0[e] + a1[e] + bias2;
              float ex = __expf(2.f * pre);
              float gv = 1.f - 2.f / (ex + 1.f);      // tanh, overflow-safe
              float hn = zreg[e] * hreg[e] + (1.f - zreg[e]) * gv;
              hreg[e] = hn;
              st_b16_llc(&hout[b * 1024 + n_own], f2b(hn));
              if (t == 511) hid[b * 2048 + n_own] = hn;
            }
          }
        }
      }
    } else {
      if (t >= 1) {
        const int s = t - 1;
        if (ph == 0) {
          const u16* hp = h0buf + (s & 1) * 32768;
          #pragma unroll
          for (int j = 0; j < 32; ++j)
            h0f[j] = ld_frag_llc(hp + (size_t)brow * 1024 + j * 32 + q * 8);
          f32x4 a0 = {0.f,0.f,0.f,0.f}, a1 = {0.f,0.f,0.f,0.f};
          #pragma unroll
          for (int ks = 0; ks < 32; ++ks) {
            bf16x8 af = ld_frag_llc(hb1 + (size_t)brow * 1024 + ks * 32 + q * 8);
            a0 = __builtin_amdgcn_mfma_f32_16x16x32_bf16(af, *(const bf16x8*)&zr_frag[ks * 512 + lane * 8], a0, 0, 0, 0);
          }
          #pragma unroll
          for (int ks = 32; ks < 64; ++ks)
            a1 = __builtin_amdgcn_mfma_f32_16x16x32_bf16(h0f[ks - 32], *(const bf16x8*)&zr_frag[ks * 512 + lane * 8], a1, 0, 0, 0);
          float hsh[4];
          #pragma unroll
          for (int e = 0; e < 4; ++e) hsh[e] = __shfl_xor(hreg[e], 8);
          #pragma unroll
          for (int e = 0; e < 4; ++e) {
            float pre = a0[e] + a1[e] + bias1;
            float sg = 1.f / (1.f + __expf(-pre));
            if (isz) zreg[e] = sg;
            else st_b16_llc(&rh1b[(w * 16 + q * 4 + e) * 1024 + n_own], f2b(sg * hsh[e]));
          }
        } else {
          f32x4 a0 = {0.f,0.f,0.f,0.f}, a1 = {0.f,0.f,0.f,0.f};
          #pragma unroll
          for (int ks = 0; ks < 32; ++ks) {
            bf16x8 af = ld_frag_llc(rh1b + (size_t)brow * 1024 + ks * 32 + q * 8);
            a0 = __builtin_amdgcn_mfma_f32_16x16x32_bf16(af, *(const bf16x8*)&g_frag[ks * 256 + (q * 8 + nl) * 8], a0, 0, 0, 0);
          }
          #pragma unroll
          for (int ks = 32; ks < 64; ++ks)
            a1 = __builtin_amdgcn_mfma_f32_16x16x32_bf16(h0f[ks - 32], *(const bf16x8*)&g_frag[ks * 256 + (q * 8 + nl) * 8], a1, 0, 0, 0);
          if (isz) {
            #pragma unroll
            for (int e = 0; e < 4; ++e) {
              int b = w * 16 + q * 4 + e;
              float pre = a0[e] + a1[e] + bias2;
              float ex = __expf(2.f * pre);
              float gv = 1.f - 2.f / (ex + 1.f);
              float hn = zreg[e] * hreg[e] + (1.f - zreg[e]) * gv;
              hreg[e] = hn;
              u16 hnb = f2b(hn);
              st_b16_llc(&hb1[b * 1024 + n_own], hnb);
              seq1[((size_t)b * 512 + s) * 1024 + n_own] = hnb;   // plain store
              if (s == 511) hid[1024 + b * 2048 + n_own] = hn;
            }
          }
        }
      }
    }
    // Last interval needs no barrier: kernel boundary orders seq1/hid for gemm_bt.
    if (p < 1025) wg_bar(cnt, p + 1, bid, lane, tid);
  }
}

// ---------------- host ----------------
extern "C" void kernel_launch(void* const* d_in, const int* in_sizes, int n_in,
                              void* d_out, int out_size, void* d_ws, size_t ws_size,
                              hipStream_t stream) {
  (void)in_sizes; (void)n_in; (void)out_size; (void)ws_size;
  char* ws = (char*)d_ws;
  const size_t MB = 1024ull * 1024ull;
  u16* seq1 = (u16*)(ws + 0);                         // 32 MB
  u16* xb   = (u16*)(ws + 32 * MB);                   // 4 MB
  u16* Wh0  = (u16*)(ws + 36 * MB);                   // 6 MB
  u16* Wh1  = (u16*)(ws + 42 * MB);                   // 6 MB
  u16* Wx0  = (u16*)(ws + 48 * MB);                   // 0.75 MB
  u16* Wx1  = (u16*)(ws + 49 * MB);                   // 6 MB
  u16* Wyb  = (u16*)(ws + 55 * MB);                   // 0.25 MB
  u16* h0buf = (u16*)(ws + 56 * MB);                  // 2 x 64 KB
  u16* hb1  = (u16*)(ws + 56 * MB + 128 * 1024);      // 64 KB
  u16* rh0b = (u16*)(ws + 56 * MB + 192 * 1024);      // 64 KB
  u16* rh1b = (u16*)(ws + 56 * MB + 256 * 1024);      // 64 KB
  u32* cnt  = (u32*)(ws + 56 * MB + 320 * 1024);      // 1026 epochs x 32B = 33 KB

  hipMemsetAsync(cnt, 0, 40 * 1024, stream);

  auto cast = [&](const void* in, u16* out, int n) {
    cast_f32_bf16<<<(n + 255) / 256, 256, 0, stream>>>((const float*)in, out, n);
  };
  cast(d_in[0], xb, 2097152);                               // x
  cast(d_in[3],  Wh0 + 0,       1048576);                   // Whz0
  cast(d_in[6],  Wh0 + 1048576, 1048576);                   // Whr0
  cast(d_in[9],  Wh0 + 2097152, 1048576);                   // Whg0
  cast(d_in[12], Wh1 + 0,       1048576);                   // Whz1
  cast(d_in[15], Wh1 + 1048576, 1048576);                   // Whr1
  cast(d_in[18], Wh1 + 2097152, 1048576);                   // Whg1
  cast(d_in[2],  Wx0 + 0,      131072);                     // Wxz0
  cast(d_in[5],  Wx0 + 131072, 131072);                     // Wxr0
  cast(d_in[8],  Wx0 + 262144, 131072);                     // Wxg0
  cast(d_in[11], Wx1 + 0,       1048576);                   // Wxz1
  cast(d_in[14], Wx1 + 1048576, 1048576);                   // Wxr1
  cast(d_in[17], Wx1 + 2097152, 1048576);                   // Wxg1
  cast(d_in[20], Wyb, 131072);                              // Wy

  float* y_out = (float*)d_out;
  float* hid = y_out + 2097152;                             // hidden (32,2,1024)

  gru_pipe<<<256, dim3(128), 0, stream>>>(
      Wh0, Wx0, Wh1, Wx1,
      (const float*)d_in[4],  (const float*)d_in[7],  (const float*)d_in[10],
      (const float*)d_in[13], (const float*)d_in[16], (const float*)d_in[19],
      xb, (const float*)d_in[1],
      h0buf, hb1, rh0b, rh1b, seq1, hid, cnt);

  // output projection y = seq1 @ Wy^T + by  (M=16384, N=128, K=1024)
  gemm_bt<<<dim3(128, 1), dim3(256), 0, stream>>>(
      seq1, Wyb, 16384, 128, 1024, (const float*)d_in[21], y_out);
}

// Round 3
// 9789.619 us; speedup vs baseline: 1.6870x; 1.6870x over previous
//
#include <hip/hip_runtime.h>

typedef unsigned short u16;
typedef unsigned int u32;
typedef unsigned long long u64;
typedef __bf16 bf16x8 __attribute__((ext_vector_type(8)));
typedef float f32x4 __attribute__((ext_vector_type(4)));

union FU { f32x4 f; bf16x8 h; };

__device__ __forceinline__ u16 f2b(float f) {
  unsigned u = __float_as_uint(f);
  return (u16)((u + 0x7fffu + ((u >> 16) & 1u)) >> 16);
}

// per-lane coherent 2B store (epilogue h publish; low volume)
__device__ __forceinline__ void st_b16_llc(u16* p, u16 v) {
  __hip_atomic_store(p, v, __ATOMIC_RELAXED, __HIP_MEMORY_SCOPE_AGENT);
}

// barrier poll: ONE plain sc0/sc1 dwordx4 per lane (coalesced normal read path,
// coherent at MALL). Data valid on return (internal vmcnt(0); only used when
// no other vmem is outstanding -- after barrier-entry syncthreads drain).
__device__ __forceinline__ uint4 ld_poll(const u32* p) {
  uint4 v;
  asm volatile("global_load_dwordx4 %0, %1, off sc0 sc1\n\ts_waitcnt vmcnt(0)"
               : "=v"(v) : "v"(p) : "memory");
  return v;
}

// issue 8 coherent 16B loads (covers 8 k-steps = 256 u16); valid after WAITV
#define ISSUE8CC(D, P)                                                       \
  asm volatile(                                                              \
      "global_load_dwordx4 %0, %8, off sc0 sc1\n\t"                          \
      "global_load_dwordx4 %1, %8, off offset:64 sc0 sc1\n\t"                \
      "global_load_dwordx4 %2, %8, off offset:128 sc0 sc1\n\t"               \
      "global_load_dwordx4 %3, %8, off offset:192 sc0 sc1\n\t"               \
      "global_load_dwordx4 %4, %8, off offset:256 sc0 sc1\n\t"               \
      "global_load_dwordx4 %5, %8, off offset:320 sc0 sc1\n\t"               \
      "global_load_dwordx4 %6, %8, off offset:384 sc0 sc1\n\t"               \
      "global_load_dwordx4 %7, %8, off offset:448 sc0 sc1"                   \
      : "=&v"((D)[0].f), "=&v"((D)[1].f), "=&v"((D)[2].f), "=&v"((D)[3].f),  \
        "=&v"((D)[4].f), "=&v"((D)[5].f), "=&v"((D)[6].f), "=&v"((D)[7].f)   \
      : "v"(P) : "memory")

// issue 4 cached 16B loads (read-only x data; counted in vmcnt like the rest)
#define ISSUE4C(D, P)                                                        \
  asm volatile(                                                              \
      "global_load_dwordx4 %0, %4, off\n\t"                                  \
      "global_load_dwordx4 %1, %4, off offset:64\n\t"                        \
      "global_load_dwordx4 %2, %4, off offset:128\n\t"                       \
      "global_load_dwordx4 %3, %4, off offset:192"                           \
      : "=&v"((D)[0].f), "=&v"((D)[1].f), "=&v"((D)[2].f), "=&v"((D)[3].f)   \
      : "v"(P) : "memory")

// counted wait + hard scheduling fence (rule #18: consumers stay below)
#define WAITV(N)                                                             \
  do {                                                                       \
    asm volatile("s_waitcnt vmcnt(" #N ")" ::: "memory");                    \
    __builtin_amdgcn_sched_barrier(0);                                       \
  } while (0)

// 8 MFMAs: A-frags from BUF, B-frags from LDS (zr layout / g layout)
#define MFMA8ZR(ACC, BUF, KSB)                                               \
  do {                                                                       \
    _Pragma("unroll") for (int j_ = 0; j_ < 8; ++j_)                         \
        ACC = __builtin_amdgcn_mfma_f32_16x16x32_bf16(                       \
            (BUF)[j_].h,                                                     \
            *(const bf16x8*)&zr_frag[(KSB + j_) * 512 + lane * 8],           \
            ACC, 0, 0, 0);                                                   \
  } while (0)
#define MFMA8G(ACC, BUF, KSB)                                                \
  do {                                                                       \
    _Pragma("unroll") for (int j_ = 0; j_ < 8; ++j_)                         \
        ACC = __builtin_amdgcn_mfma_f32_16x16x32_bf16(                       \
            (BUF)[j_].h,                                                     \
            *(const bf16x8*)&g_frag[(KSB + j_) * 256 + boff],                \
            ACC, 0, 0, 0);                                                   \
  } while (0)

// ---------------- generic fp32 -> bf16 cast ----------------
__global__ void cast_f32_bf16(const float* __restrict__ in, u16* __restrict__ out, int n) {
  int i = blockIdx.x * 256 + threadIdx.x;
  if (i < n) out[i] = f2b(in[i]);
}

// ---------------- device barrier over 256 wgs (known-good shape) ----------------
// Entry __syncthreads drains both waves' vmcnt (publishes payload at LLC).
// tid0 stores the wg's slot (relaxed agent atomic; 1 op per wg, negligible).
// Wave 0 polls all 256 slots with one plain-sc dwordx4 per lane, then the
// trailing __syncthreads releases wave 1. Slots are monotone epochs (no ABA).
__device__ __forceinline__ void wg_bar(u32* __restrict__ slots, u32 ep,
                                       int bid, int tid, int lane, int w) {
  __syncthreads();
  if (tid == 0)
    __hip_atomic_store(&slots[bid], ep, __ATOMIC_RELAXED, __HIP_MEMORY_SCOPE_AGENT);
  if (w == 0) {
    for (;;) {
      uint4 v = ld_poll(&slots[lane * 4]);
      u32 m = min(min(v.x, v.y), min(v.z, v.w));
      if (__all(m >= ep)) break;
      __builtin_amdgcn_s_sleep(1);
    }
  }
  __syncthreads();
}

// ---------------- tiled bf16 GEMM: C[M,N] = A[M,K] @ B[N,K]^T (fp32 out) ----------------
__global__ __launch_bounds__(256) void gemm_bt(
    const u16* __restrict__ A, const u16* __restrict__ B,
    int M, int N, int K,
    const float* __restrict__ bias, float* __restrict__ Cf)
{
  __shared__ u16 a_sm[128 * 32];
  __shared__ u16 b_sm[128 * 32];
  const int tid = threadIdx.x;
  const int lane = tid & 63;
  const int wid = tid >> 6;
  const int wm = wid >> 1, wn = wid & 1;
  const int m0 = blockIdx.x * 128, n0 = blockIdx.y * 128;
  const int q = lane >> 4, l15 = lane & 15, l3 = lane & 3;

  f32x4 acc[4][4];
  #pragma unroll
  for (int i = 0; i < 4; ++i)
    #pragma unroll
    for (int j = 0; j < 4; ++j) acc[i][j] = (f32x4){0.f, 0.f, 0.f, 0.f};

  for (int kk = 0; kk < K; kk += 32) {
    __syncthreads();
    #pragma unroll
    for (int p = 0; p < 2; ++p) {
      int idx = p * 256 + tid;
      int r = idx >> 2, cch = idx & 3;
      *(uint4*)&a_sm[r * 32 + ((cch ^ (r & 3)) * 8)] =
          *(const uint4*)&A[(size_t)(m0 + r) * K + kk + cch * 8];
      *(uint4*)&b_sm[r * 32 + ((cch ^ (r & 3)) * 8)] =
          *(const uint4*)&B[(size_t)(n0 + r) * K + kk + cch * 8];
    }
    __syncthreads();
    bf16x8 af[4], bfr[4];
    #pragma unroll
    for (int s = 0; s < 4; ++s) {
      int ra = wm * 64 + s * 16 + l15;
      af[s] = *(const bf16x8*)&a_sm[ra * 32 + ((q ^ l3) * 8)];
      int rb = wn * 64 + s * 16 + l15;
      bfr[s] = *(const bf16x8*)&b_sm[rb * 32 + ((q ^ l3) * 8)];
    }
    #pragma unroll
    for (int si = 0; si < 4; ++si)
      #pragma unroll
      for (int sj = 0; sj < 4; ++sj)
        acc[si][sj] = __builtin_amdgcn_mfma_f32_16x16x32_bf16(af[si], bfr[sj], acc[si][sj], 0, 0, 0);
  }

  #pragma unroll
  for (int si = 0; si < 4; ++si)
    #pragma unroll
    for (int sj = 0; sj < 4; ++sj)
      #pragma unroll
      for (int e = 0; e < 4; ++e) {
        int m = m0 + wm * 64 + si * 16 + q * 4 + e;
        int n = n0 + wn * 64 + sj * 16 + l15;
        Cf[(size_t)m * N + n] = acc[si][sj][e] + (bias ? bias[n] : 0.f);
      }
}

// ---------------- fused 2-layer pipelined GRU: 1026 device barriers total ----------------
// 256 wgs x 128 thr. wgs 0-127: layer 0 (n-slice 8 each, K=1024+128 concat [Wh0|Wx0]).
// wgs 128-255: layer 1, one step behind (K=1024+1024 concat [Wh1|Wx1], x-input = h0_t).
// h exchange: plain sc0/sc1 (MALL-coherent) 16B loads, 3 rotating 8-frag groups
// with counted vmcnt -- wave-coalesced (16 lines/frag-set) vs per-lane atomics.
__global__ __launch_bounds__(128, 1) void gru_pipe(
    const u16* __restrict__ Wh0, const u16* __restrict__ Wx0,
    const u16* __restrict__ Wh1, const u16* __restrict__ Wx1,
    const float* __restrict__ bz0, const float* __restrict__ br0, const float* __restrict__ bg0,
    const float* __restrict__ bz1, const float* __restrict__ br1, const float* __restrict__ bg1,
    const u16* __restrict__ xb,                      // [32][512][128] bf16
    const float* __restrict__ h0p,                   // (32,2,1024) fp32
    u16* __restrict__ h0buf,                         // 2 x [32][1024] bf16 rotating
    u16* __restrict__ hb1,                           // [32][1024]
    u16* __restrict__ rh0b, u16* __restrict__ rh1b,  // [32][1024]
    u16* __restrict__ seq1,                          // [32][512][1024] bf16
    float* __restrict__ hid,                         // (32,2,1024) fp32 out
    u32* __restrict__ slots)                         // 256 wg slots
{
  __shared__ u16 zr_frag[64 * 512];                  // 64 KB max (L1)
  __shared__ u16 g_frag[64 * 256];                   // 32 KB max

  const int tid = threadIdx.x;
  const int lane = tid & 63;
  const int w = tid >> 6;
  const int bid = blockIdx.x;
  const bool Lyr1 = bid >= 128;
  const int nb = (bid & 127) * 8;
  const int q = lane >> 4, c15 = lane & 15, nl = c15 & 7;
  const int n_own = nb + nl;
  const bool isz = c15 < 8;
  const int brow = w * 16 + c15;                     // A-fragment batch row
  const int boff = (q * 8 + nl) * 8;                 // g_frag B-fragment offset
  const int aoff = brow * 1024 + q * 8;              // A-fragment element offset
  const int KS = Lyr1 ? 64 : 36;                     // K-steps of 32
  const int IN = Lyr1 ? 1024 : 128;
  const u16* Wh = Lyr1 ? Wh1 : Wh0;
  const u16* Wx = Lyr1 ? Wx1 : Wx0;
  const size_t WXG = (size_t)1024 * IN;              // Wx per-gate elems

  // ---- stage concat [Wh | Wx] weights into LDS in MFMA B-frag order ----
  for (int cidx = tid; cidx < KS * 64; cidx += 128) {
    int ks = cidx >> 6, l = cidx & 63;
    int lq = l >> 4, lc = l & 15;
    int row = nb + (lc & 7), gate = (lc < 8) ? 0 : 1;  // z | r
    int k0 = ks * 32 + lq * 8;
    const u16* src = (k0 < 1024)
        ? Wh + (size_t)gate * 1048576 + (size_t)row * 1024 + k0
        : Wx + (size_t)gate * WXG + (size_t)row * IN + (k0 - 1024);
    *(uint4*)&zr_frag[cidx * 8] = *(const uint4*)src;
  }
  for (int gidx = tid; gidx < KS * 32; gidx += 128) {
    int ks = gidx >> 5, s = gidx & 31;
    int lq = s >> 3, r8 = s & 7;
    int row = nb + r8, k0 = ks * 32 + lq * 8;
    const u16* src = (k0 < 1024)
        ? Wh + (size_t)2 * 1048576 + (size_t)row * 1024 + k0
        : Wx + (size_t)2 * WXG + (size_t)row * IN + (k0 - 1024);
    *(uint4*)&g_frag[gidx * 8] = *(const uint4*)src;
  }

  // ---- biases ----
  const float bias1 = isz ? (Lyr1 ? bz1 : bz0)[n_own] : (Lyr1 ? br1 : br0)[n_own];
  const float bias2 = (Lyr1 ? bg1 : bg0)[n_own];

  // ---- init state: z-lanes hold h fp32; publish bf16 ----
  float hreg[4], zreg[4] = {0.f, 0.f, 0.f, 0.f};
  #pragma unroll
  for (int e = 0; e < 4; ++e) {
    int b = w * 16 + q * 4 + e;
    float v = h0p[b * 2048 + (Lyr1 ? 1024 : 0) + n_own];
    hreg[e] = v;
    if (isz)
      st_b16_llc((Lyr1 ? hb1 : h0buf + 32768) + b * 1024 + n_own, f2b(v));
  }
  wg_bar(slots, 1, bid, tid, lane, w);

  FU xfu[4];                                         // L0: x frags, live both phases
  FU sA[8], sB[8], sC[8];                            // rotating stream groups (96 VGPR)

  for (int p = 0; p < 1026; ++p) {
    const int t = p >> 1, ph = p & 1;
    if (!Lyr1) {
      if (t < 512) {
        f32x4 a0 = {0.f,0.f,0.f,0.f}, a1 = {0.f,0.f,0.f,0.f};
        if (ph == 0) {
          const u16* hp = h0buf + ((t - 1) & 1) * 32768 + aoff;
          const u16* xp = xb + ((size_t)brow * 512 + t) * 128 + q * 8;
          ISSUE4C(xfu, xp);                          // 4 out
          ISSUE8CC(sA, hp);                          // 12
          ISSUE8CC(sB, hp + 256);                    // 20
          ISSUE8CC(sC, hp + 512);                    // 28
          WAITV(16); MFMA8ZR(a0, sA, 0);             // xfu+sA done
          ISSUE8CC(sA, hp + 768);                    // 24
          WAITV(16); MFMA8ZR(a0, sB, 8);
          WAITV(8);  MFMA8ZR(a0, sC, 16);
          WAITV(0);  MFMA8ZR(a0, sA, 24);
          #pragma unroll
          for (int j = 0; j < 4; ++j)
            a1 = __builtin_amdgcn_mfma_f32_16x16x32_bf16(
                xfu[j].h, *(const bf16x8*)&zr_frag[(32 + j) * 512 + lane * 8], a1, 0, 0, 0);
          float hsh[4];
          #pragma unroll
          for (int e = 0; e < 4; ++e) hsh[e] = __shfl_xor(hreg[e], 8);
          #pragma unroll
          for (int e = 0; e < 4; ++e) {
            float pre = a0[e] + a1[e] + bias1;
            float s = 1.f / (1.f + __expf(-pre));
            if (isz) zreg[e] = s;
            else st_b16_llc(&rh0b[(w * 16 + q * 4 + e) * 1024 + n_own], f2b(s * hsh[e]));
          }
        } else {
          const u16* rp = rh0b + aoff;
          ISSUE8CC(sA, rp);                          // 8
          ISSUE8CC(sB, rp + 256);                    // 16
          ISSUE8CC(sC, rp + 512);                    // 24
          WAITV(16); MFMA8G(a0, sA, 0);
          ISSUE8CC(sA, rp + 768);                    // 24
          WAITV(16); MFMA8G(a0, sB, 8);
          WAITV(8);  MFMA8G(a0, sC, 16);
          WAITV(0);  MFMA8G(a0, sA, 24);
          #pragma unroll
          for (int j = 0; j < 4; ++j)
            a1 = __builtin_amdgcn_mfma_f32_16x16x32_bf16(
                xfu[j].h, *(const bf16x8*)&g_frag[(32 + j) * 256 + boff], a1, 0, 0, 0);
          if (isz) {
            u16* hout = h0buf + (t & 1) * 32768;
            #pragma unroll
            for (int e = 0; e < 4; ++e) {
              int b = w * 16 + q * 4 + e;
              float pre = a0[e] + a1[e] + bias2;
              float ex = __expf(2.f * pre);
              float gv = 1.f - 2.f / (ex + 1.f);      // tanh, overflow-safe
              float hn = zreg[e] * hreg[e] + (1.f - zreg[e]) * gv;
              hreg[e] = hn;
              st_b16_llc(&hout[b * 1024 + n_own], f2b(hn));
              if (t == 511) hid[b * 2048 + n_own] = hn;
            }
          }
        }
      }
    } else {
      if (t >= 1) {
        const int s = t - 1;
        f32x4 a0 = {0.f,0.f,0.f,0.f}, a1 = {0.f,0.f,0.f,0.f};
        const u16* hp = h0buf + (s & 1) * 32768 + aoff;
        if (ph == 0) {
          const u16* hb = hb1 + aoff;
          ISSUE8CC(sA, hb);                          // 8
          ISSUE8CC(sB, hb + 256);                    // 16
          ISSUE8CC(sC, hb + 512);                    // 24
          WAITV(16); MFMA8ZR(a0, sA, 0);  ISSUE8CC(sA, hb + 768);   // 24
          WAITV(16); MFMA8ZR(a0, sB, 8);  ISSUE8CC(sB, hp);         // 24
          WAITV(16); MFMA8ZR(a0, sC, 16); ISSUE8CC(sC, hp + 256);   // 24
          WAITV(16); MFMA8ZR(a0, sA, 24); ISSUE8CC(sA, hp + 512);   // 24
          WAITV(16); MFMA8ZR(a1, sB, 32); ISSUE8CC(sB, hp + 768);   // 24
          WAITV(16); MFMA8ZR(a1, sC, 40);
          WAITV(8);  MFMA8ZR(a1, sA, 48);
          WAITV(0);  MFMA8ZR(a1, sB, 56);
          float hsh[4];
          #pragma unroll
          for (int e = 0; e < 4; ++e) hsh[e] = __shfl_xor(hreg[e], 8);
          #pragma unroll
          for (int e = 0; e < 4; ++e) {
            float pre = a0[e] + a1[e] + bias1;
            float sg = 1.f / (1.f + __expf(-pre));
            if (isz) zreg[e] = sg;
            else st_b16_llc(&rh1b[(w * 16 + q * 4 + e) * 1024 + n_own], f2b(sg * hsh[e]));
          }
        } else {
          const u16* rp = rh1b + aoff;
          ISSUE8CC(sA, rp);                          // 8
          ISSUE8CC(sB, rp + 256);                    // 16
          ISSUE8CC(sC, rp + 512);                    // 24
          WAITV(16); MFMA8G(a0, sA, 0);  ISSUE8CC(sA, rp + 768);    // 24
          WAITV(16); MFMA8G(a0, sB, 8);  ISSUE8CC(sB, hp);          // 24
          WAITV(16); MFMA8G(a0, sC, 16); ISSUE8CC(sC, hp + 256);    // 24
          WAITV(16); MFMA8G(a0, sA, 24); ISSUE8CC(sA, hp + 512);    // 24
          WAITV(16); MFMA8G(a1, sB, 32); ISSUE8CC(sB, hp + 768);    // 24
          WAITV(16); MFMA8G(a1, sC, 40);
          WAITV(8);  MFMA8G(a1, sA, 48);
          WAITV(0);  MFMA8G(a1, sB, 56);
          if (isz) {
            #pragma unroll
            for (int e = 0; e < 4; ++e) {
              int b = w * 16 + q * 4 + e;
              float pre = a0[e] + a1[e] + bias2;
              float ex = __expf(2.f * pre);
              float gv = 1.f - 2.f / (ex + 1.f);
              float hn = zreg[e] * hreg[e] + (1.f - zreg[e]) * gv;
              hreg[e] = hn;
              u16 hnb = f2b(hn);
              st_b16_llc(&hb1[b * 1024 + n_own], hnb);
              seq1[((size_t)b * 512 + s) * 1024 + n_own] = hnb;   // plain store
              if (s == 511) hid[1024 + b * 2048 + n_own] = hn;
            }
          }
        }
      }
    }
    // Last interval needs no barrier: kernel boundary orders seq1/hid for gemm_bt.
    if (p < 1025) wg_bar(slots, (u32)(p + 2), bid, tid, lane, w);
  }
}

// ---------------- host ----------------
extern "C" void kernel_launch(void* const* d_in, const int* in_sizes, int n_in,
                              void* d_out, int out_size, void* d_ws, size_t ws_size,
                              hipStream_t stream) {
  (void)in_sizes; (void)n_in; (void)out_size; (void)ws_size;
  char* ws = (char*)d_ws;
  const size_t MB = 1024ull * 1024ull;
  u16* seq1 = (u16*)(ws + 0);                         // 32 MB
  u16* xb   = (u16*)(ws + 32 * MB);                   // 4 MB
  u16* Wh0  = (u16*)(ws + 36 * MB);                   // 6 MB
  u16* Wh1  = (u16*)(ws + 42 * MB);                   // 6 MB
  u16* Wx0  = (u16*)(ws + 48 * MB);                   // 0.75 MB
  u16* Wx1  = (u16*)(ws + 49 * MB);                   // 6 MB
  u16* Wyb  = (u16*)(ws + 55 * MB);                   // 0.25 MB
  u16* h0buf = (u16*)(ws + 56 * MB);                  // 2 x 64 KB
  u16* hb1  = (u16*)(ws + 56 * MB + 128 * 1024);      // 64 KB
  u16* rh0b = (u16*)(ws + 56 * MB + 192 * 1024);      // 64 KB
  u16* rh1b = (u16*)(ws + 56 * MB + 256 * 1024);      // 64 KB
  u32* slots = (u32*)(ws + 56 * MB + 320 * 1024);     // 1 KB

  hipMemsetAsync(slots, 0, 1024, stream);

  auto cast = [&](const void* in, u16* out, int n) {
    cast_f32_bf16<<<(n + 255) / 256, 256, 0, stream>>>((const float*)in, out, n);
  };
  cast(d_in[0], xb, 2097152);                               // x
  cast(d_in[3],  Wh0 + 0,       1048576);                   // Whz0
  cast(d_in[6],  Wh0 + 1048576, 1048576);                   // Whr0
  cast(d_in[9],  Wh0 + 2097152, 1048576);                   // Whg0
  cast(d_in[12], Wh1 + 0,       1048576);                   // Whz1
  cast(d_in[15], Wh1 + 1048576, 1048576);                   // Whr1
  cast(d_in[18], Wh1 + 2097152, 1048576);                   // Whg1
  cast(d_in[2],  Wx0 + 0,      131072);                     // Wxz0
  cast(d_in[5],  Wx0 + 131072, 131072);                     // Wxr0
  cast(d_in[8],  Wx0 + 262144, 131072);                     // Wxg0
  cast(d_in[11], Wx1 + 0,       1048576);                   // Wxz1
  cast(d_in[14], Wx1 + 1048576, 1048576);                   // Wxr1
  cast(d_in[17], Wx1 + 2097152, 1048576);                   // Wxg1
  cast(d_in[20], Wyb, 131072);                              // Wy

  float* y_out = (float*)d_out;
  float* hid = y_out + 2097152;                             // hidden (32,2,1024)

  gru_pipe<<<256, dim3(128), 0, stream>>>(
      Wh0, Wx0, Wh1, Wx1,
      (const float*)d_in[4],  (const float*)d_in[7],  (const float*)d_in[10],
      (const float*)d_in[13], (const float*)d_in[16], (const float*)d_in[19],
      xb, (const float*)d_in[1],
      h0buf, hb1, rh0b, rh1b, seq1, hid, slots);

  // output projection y = seq1 @ Wy^T + by  (M=16384, N=128, K=1024)
  gemm_bt<<<dim3(128, 1), dim3(256), 0, stream>>>(
      seq1, Wyb, 16384, 128, 1024, (const float*)d_in[21], y_out);
}

// Round 5
// 6572.026 us; speedup vs baseline: 2.5129x; 1.4896x over previous
//
#include <hip/hip_runtime.h>

typedef unsigned short u16;
typedef unsigned int u32;
typedef unsigned long long u64;
typedef __bf16 bf16x8 __attribute__((ext_vector_type(8)));
typedef float f32x4 __attribute__((ext_vector_type(4)));

union FU { f32x4 f; bf16x8 h; };

__device__ __forceinline__ u16 f2b(float f) {
  unsigned u = __float_as_uint(f);
  return (u16)((u + 0x7fffu + ((u >> 16) & 1u)) >> 16);
}

// per-lane coherent 2B store (epilogue h publish; low volume)
__device__ __forceinline__ void st_b16_llc(u16* p, u16 v) {
  __hip_atomic_store(p, v, __ATOMIC_RELAXED, __HIP_MEMORY_SCOPE_AGENT);
}

// coherent dword load (poll path; valid on return)
__device__ __forceinline__ u32 ld_dword_cc(const u32* p) {
  u32 v;
  asm volatile("global_load_dword %0, %1, off sc0 sc1\n\ts_waitcnt vmcnt(0)"
               : "=v"(v) : "v"(p) : "memory");
  return v;
}

// issue 8 coherent 16B loads (covers 8 k-steps = 256 u16); valid after WAITV
#define ISSUE8CC(D, P)                                                       \
  asm volatile(                                                              \
      "global_load_dwordx4 %0, %8, off sc0 sc1\n\t"                          \
      "global_load_dwordx4 %1, %8, off offset:64 sc0 sc1\n\t"                \
      "global_load_dwordx4 %2, %8, off offset:128 sc0 sc1\n\t"               \
      "global_load_dwordx4 %3, %8, off offset:192 sc0 sc1\n\t"               \
      "global_load_dwordx4 %4, %8, off offset:256 sc0 sc1\n\t"               \
      "global_load_dwordx4 %5, %8, off offset:320 sc0 sc1\n\t"               \
      "global_load_dwordx4 %6, %8, off offset:384 sc0 sc1\n\t"               \
      "global_load_dwordx4 %7, %8, off offset:448 sc0 sc1"                   \
      : "=&v"((D)[0].f), "=&v"((D)[1].f), "=&v"((D)[2].f), "=&v"((D)[3].f),  \
        "=&v"((D)[4].f), "=&v"((D)[5].f), "=&v"((D)[6].f), "=&v"((D)[7].f)   \
      : "v"(P) : "memory")

// issue 4 cached 16B loads (read-only x data; counted in vmcnt like the rest)
#define ISSUE4C(D, P)                                                        \
  asm volatile(                                                              \
      "global_load_dwordx4 %0, %4, off\n\t"                                  \
      "global_load_dwordx4 %1, %4, off offset:64\n\t"                        \
      "global_load_dwordx4 %2, %4, off offset:128\n\t"                       \
      "global_load_dwordx4 %3, %4, off offset:192"                           \
      : "=&v"((D)[0].f), "=&v"((D)[1].f), "=&v"((D)[2].f), "=&v"((D)[3].f)   \
      : "v"(P) : "memory")

// counted wait + hard scheduling fence (rule #18: consumers stay below)
#define WAITV(N)                                                             \
  do {                                                                       \
    asm volatile("s_waitcnt vmcnt(" #N ")" ::: "memory");                    \
    __builtin_amdgcn_sched_barrier(0);                                       \
  } while (0)

// 8 MFMAs: A-frags from BUF, B-frags from LDS (zr layout / g layout)
#define MFMA8ZR(ACC, BUF, KSB)                                               \
  do {                                                                       \
    _Pragma("unroll") for (int j_ = 0; j_ < 8; ++j_)                         \
        ACC = __builtin_amdgcn_mfma_f32_16x16x32_bf16(                       \
            (BUF)[j_].h,                                                     \
            *(const bf16x8*)&zr_frag[(KSB + j_) * 512 + lane * 8],           \
            ACC, 0, 0, 0);                                                   \
  } while (0)
#define MFMA8G(ACC, BUF, KSB)                                                \
  do {                                                                       \
    _Pragma("unroll") for (int j_ = 0; j_ < 8; ++j_)                         \
        ACC = __builtin_amdgcn_mfma_f32_16x16x32_bf16(                       \
            (BUF)[j_].h,                                                     \
            *(const bf16x8*)&g_frag[(KSB + j_) * 256 + boff],                \
            ACC, 0, 0, 0);                                                   \
  } while (0)

// ---------------- generic fp32 -> bf16 cast ----------------
__global__ void cast_f32_bf16(const float* __restrict__ in, u16* __restrict__ out, int n) {
  int i = blockIdx.x * 256 + threadIdx.x;
  if (i < n) out[i] = f2b(in[i]);
}

// ---------------- hierarchical device barrier over 256 wgs ----------------
// Level 1: 8 groups x 32 wgs. tid0 stores epoch to its group slot (after
// __syncthreads drains both waves' payload stores to the MALL). Group leader's
// wave0 polls its 32 slots (2 lines, lanes 0-31), then lane0 publishes the
// epoch to gslots[g]. Level 2: every wg's wave0 polls gslots -- ONE cache line
// (8 u32, broadcast read) -- vs the flat barrier's 16-line x 256-wave scan.
// Monotone epochs (no reset/ABA). Transitivity: all meets at the MALL.
__device__ __forceinline__ void wg_bar(u32* __restrict__ slots, u32 ep,
                                       int bid, int tid, int lane, int w) {
  __syncthreads();
  const int g = bid >> 5;
  u32* gslots = slots + 256;                           // own 128B line
  if (tid == 0)
    __hip_atomic_store(&slots[g * 32 + (bid & 31)], ep,
                       __ATOMIC_RELAXED, __HIP_MEMORY_SCOPE_AGENT);
  if (w == 0) {
    if ((bid & 31) == 0) {
      const u32* grp = slots + g * 32;
      for (;;) {
        u32 v = ep;
        if (lane < 32) v = ld_dword_cc(&grp[lane]);
        if (__all(v >= ep)) break;
        __builtin_amdgcn_s_sleep(1);
      }
      if (lane == 0)
        __hip_atomic_store(&gslots[g], ep,
                           __ATOMIC_RELAXED, __HIP_MEMORY_SCOPE_AGENT);
    }
    for (;;) {
      u32 v = ld_dword_cc(&gslots[lane & 7]);
      if (__all(v >= ep)) break;
      __builtin_amdgcn_s_sleep(1);
    }
  }
  __syncthreads();
}

// ---------------- tiled bf16 GEMM: C[M,N] = A[M,K] @ B[N,K]^T (fp32 out) ----------------
__global__ __launch_bounds__(256) void gemm_bt(
    const u16* __restrict__ A, const u16* __restrict__ B,
    int M, int N, int K,
    const float* __restrict__ bias, float* __restrict__ Cf)
{
  __shared__ u16 a_sm[128 * 32];
  __shared__ u16 b_sm[128 * 32];
  const int tid = threadIdx.x;
  const int lane = tid & 63;
  const int wid = tid >> 6;
  const int wm = wid >> 1, wn = wid & 1;
  const int m0 = blockIdx.x * 128, n0 = blockIdx.y * 128;
  const int q = lane >> 4, l15 = lane & 15, l3 = lane & 3;

  f32x4 acc[4][4];
  #pragma unroll
  for (int i = 0; i < 4; ++i)
    #pragma unroll
    for (int j = 0; j < 4; ++j) acc[i][j] = (f32x4){0.f, 0.f, 0.f, 0.f};

  for (int kk = 0; kk < K; kk += 32) {
    __syncthreads();
    #pragma unroll
    for (int p = 0; p < 2; ++p) {
      int idx = p * 256 + tid;
      int r = idx >> 2, cch = idx & 3;
      *(uint4*)&a_sm[r * 32 + ((cch ^ (r & 3)) * 8)] =
          *(const uint4*)&A[(size_t)(m0 + r) * K + kk + cch * 8];
      *(uint4*)&b_sm[r * 32 + ((cch ^ (r & 3)) * 8)] =
          *(const uint4*)&B[(size_t)(n0 + r) * K + kk + cch * 8];
    }
    __syncthreads();
    bf16x8 af[4], bfr[4];
    #pragma unroll
    for (int s = 0; s < 4; ++s) {
      int ra = wm * 64 + s * 16 + l15;
      af[s] = *(const bf16x8*)&a_sm[ra * 32 + ((q ^ l3) * 8)];
      int rb = wn * 64 + s * 16 + l15;
      bfr[s] = *(const bf16x8*)&b_sm[rb * 32 + ((q ^ l3) * 8)];
    }
    #pragma unroll
    for (int si = 0; si < 4; ++si)
      #pragma unroll
      for (int sj = 0; sj < 4; ++sj)
        acc[si][sj] = __builtin_amdgcn_mfma_f32_16x16x32_bf16(af[si], bfr[sj], acc[si][sj], 0, 0, 0);
  }

  #pragma unroll
  for (int si = 0; si < 4; ++si)
    #pragma unroll
    for (int sj = 0; sj < 4; ++sj)
      #pragma unroll
      for (int e = 0; e < 4; ++e) {
        int m = m0 + wm * 64 + si * 16 + q * 4 + e;
        int n = n0 + wn * 64 + sj * 16 + l15;
        Cf[(size_t)m * N + n] = acc[si][sj][e] + (bias ? bias[n] : 0.f);
      }
}

// ---------------- fused 2-layer pipelined GRU: 1026 device barriers total ----------------
// 256 wgs x 128 thr. wgs 0-127: layer 0 (n-slice 8 each, K=1024+128 concat [Wh0|Wx0]).
// wgs 128-255: layer 1, one step behind (K=1024+1024 concat [Wh1|Wx1], x-input = h0_t).
// Payload (r3 known-good): plain sc0/sc1 16B loads, 3 rotating 8-frag groups,
// counted vmcnt ladders. Barrier: hierarchical (this round's change).
__global__ __launch_bounds__(128, 1) void gru_pipe(
    const u16* __restrict__ Wh0, const u16* __restrict__ Wx0,
    const u16* __restrict__ Wh1, const u16* __restrict__ Wx1,
    const float* __restrict__ bz0, const float* __restrict__ br0, const float* __restrict__ bg0,
    const float* __restrict__ bz1, const float* __restrict__ br1, const float* __restrict__ bg1,
    const u16* __restrict__ xb,                      // [32][512][128] bf16
    const float* __restrict__ h0p,                   // (32,2,1024) fp32
    u16* __restrict__ h0buf,                         // 2 x [32][1024] bf16 rotating
    u16* __restrict__ hb1,                           // [32][1024]
    u16* __restrict__ rh0b, u16* __restrict__ rh1b,  // [32][1024]
    u16* __restrict__ seq1,                          // [32][512][1024] bf16
    float* __restrict__ hid,                         // (32,2,1024) fp32 out
    u32* __restrict__ slots)                         // 256 L1 slots + 8 gslots
{
  __shared__ u16 zr_frag[64 * 512];                  // 64 KB max (L1)
  __shared__ u16 g_frag[64 * 256];                   // 32 KB max

  const int tid = threadIdx.x;
  const int lane = tid & 63;
  const int w = tid >> 6;
  const int bid = blockIdx.x;
  const bool Lyr1 = bid >= 128;
  const int nb = (bid & 127) * 8;
  const int q = lane >> 4, c15 = lane & 15, nl = c15 & 7;
  const int n_own = nb + nl;
  const bool isz = c15 < 8;
  const int brow = w * 16 + c15;                     // A-fragment batch row
  const int boff = (q * 8 + nl) * 8;                 // g_frag B-fragment offset
  const int aoff = brow * 1024 + q * 8;              // A-fragment element offset
  const int KS = Lyr1 ? 64 : 36;                     // K-steps of 32
  const int IN = Lyr1 ? 1024 : 128;
  const u16* Wh = Lyr1 ? Wh1 : Wh0;
  const u16* Wx = Lyr1 ? Wx1 : Wx0;
  const size_t WXG = (size_t)1024 * IN;              // Wx per-gate elems

  // ---- stage concat [Wh | Wx] weights into LDS in MFMA B-frag order ----
  for (int cidx = tid; cidx < KS * 64; cidx += 128) {
    int ks = cidx >> 6, l = cidx & 63;
    int lq = l >> 4, lc = l & 15;
    int row = nb + (lc & 7), gate = (lc < 8) ? 0 : 1;  // z | r
    int k0 = ks * 32 + lq * 8;
    const u16* src = (k0 < 1024)
        ? Wh + (size_t)gate * 1048576 + (size_t)row * 1024 + k0
        : Wx + (size_t)gate * WXG + (size_t)row * IN + (k0 - 1024);
    *(uint4*)&zr_frag[cidx * 8] = *(const uint4*)src;
  }
  for (int gidx = tid; gidx < KS * 32; gidx += 128) {
    int ks = gidx >> 5, s = gidx & 31;
    int lq = s >> 3, r8 = s & 7;
    int row = nb + r8, k0 = ks * 32 + lq * 8;
    const u16* src = (k0 < 1024)
        ? Wh + (size_t)2 * 1048576 + (size_t)row * 1024 + k0
        : Wx + (size_t)2 * WXG + (size_t)row * IN + (k0 - 1024);
    *(uint4*)&g_frag[gidx * 8] = *(const uint4*)src;
  }

  // ---- biases ----
  const float bias1 = isz ? (Lyr1 ? bz1 : bz0)[n_own] : (Lyr1 ? br1 : br0)[n_own];
  const float bias2 = (Lyr1 ? bg1 : bg0)[n_own];

  // ---- init state: z-lanes hold h fp32; publish bf16 ----
  float hreg[4], zreg[4] = {0.f, 0.f, 0.f, 0.f};
  #pragma unroll
  for (int e = 0; e < 4; ++e) {
    int b = w * 16 + q * 4 + e;
    float v = h0p[b * 2048 + (Lyr1 ? 1024 : 0) + n_own];
    hreg[e] = v;
    if (isz)
      st_b16_llc((Lyr1 ? hb1 : h0buf + 32768) + b * 1024 + n_own, f2b(v));
  }
  wg_bar(slots, 1, bid, tid, lane, w);

  FU xfu[4];                                         // L0: x frags, live both phases
  FU sA[8], sB[8], sC[8];                            // rotating stream groups (96 VGPR)

  for (int p = 0; p < 1026; ++p) {
    const int t = p >> 1, ph = p & 1;
    if (!Lyr1) {
      if (t < 512) {
        f32x4 a0 = {0.f,0.f,0.f,0.f}, a1 = {0.f,0.f,0.f,0.f};
        if (ph == 0) {
          const u16* hp = h0buf + ((t - 1) & 1) * 32768 + aoff;
          const u16* xp = xb + ((size_t)brow * 512 + t) * 128 + q * 8;
          ISSUE4C(xfu, xp);                          // 4 out
          ISSUE8CC(sA, hp);                          // 12
          ISSUE8CC(sB, hp + 256);                    // 20
          ISSUE8CC(sC, hp + 512);                    // 28
          WAITV(16); MFMA8ZR(a0, sA, 0);             // xfu+sA done
          ISSUE8CC(sA, hp + 768);                    // 24
          WAITV(16); MFMA8ZR(a0, sB, 8);
          WAITV(8);  MFMA8ZR(a0, sC, 16);
          WAITV(0);  MFMA8ZR(a0, sA, 24);
          #pragma unroll
          for (int j = 0; j < 4; ++j)
            a1 = __builtin_amdgcn_mfma_f32_16x16x32_bf16(
                xfu[j].h, *(const bf16x8*)&zr_frag[(32 + j) * 512 + lane * 8], a1, 0, 0, 0);
          float hsh[4];
          #pragma unroll
          for (int e = 0; e < 4; ++e) hsh[e] = __shfl_xor(hreg[e], 8);
          #pragma unroll
          for (int e = 0; e < 4; ++e) {
            float pre = a0[e] + a1[e] + bias1;
            float s = 1.f / (1.f + __expf(-pre));
            if (isz) zreg[e] = s;
            else st_b16_llc(&rh0b[(w * 16 + q * 4 + e) * 1024 + n_own], f2b(s * hsh[e]));
          }
        } else {
          const u16* rp = rh0b + aoff;
          ISSUE8CC(sA, rp);                          // 8
          ISSUE8CC(sB, rp + 256);                    // 16
          ISSUE8CC(sC, rp + 512);                    // 24
          WAITV(16); MFMA8G(a0, sA, 0);
          ISSUE8CC(sA, rp + 768);                    // 24
          WAITV(16); MFMA8G(a0, sB, 8);
          WAITV(8);  MFMA8G(a0, sC, 16);
          WAITV(0);  MFMA8G(a0, sA, 24);
          #pragma unroll
          for (int j = 0; j < 4; ++j)
            a1 = __builtin_amdgcn_mfma_f32_16x16x32_bf16(
                xfu[j].h, *(const bf16x8*)&g_frag[(32 + j) * 256 + boff], a1, 0, 0, 0);
          if (isz) {
            u16* hout = h0buf + (t & 1) * 32768;
            #pragma unroll
            for (int e = 0; e < 4; ++e) {
              int b = w * 16 + q * 4 + e;
              float pre = a0[e] + a1[e] + bias2;
              float ex = __expf(2.f * pre);
              float gv = 1.f - 2.f / (ex + 1.f);      // tanh, overflow-safe
              float hn = zreg[e] * hreg[e] + (1.f - zreg[e]) * gv;
              hreg[e] = hn;
              st_b16_llc(&hout[b * 1024 + n_own], f2b(hn));
              if (t == 511) hid[b * 2048 + n_own] = hn;
            }
          }
        }
      }
    } else {
      if (t >= 1) {
        const int s = t - 1;
        f32x4 a0 = {0.f,0.f,0.f,0.f}, a1 = {0.f,0.f,0.f,0.f};
        const u16* hp = h0buf + (s & 1) * 32768 + aoff;
        if (ph == 0) {
          const u16* hb = hb1 + aoff;
          ISSUE8CC(sA, hb);                          // 8
          ISSUE8CC(sB, hb + 256);                    // 16
          ISSUE8CC(sC, hb + 512);                    // 24
          WAITV(16); MFMA8ZR(a0, sA, 0);  ISSUE8CC(sA, hb + 768);   // 24
          WAITV(16); MFMA8ZR(a0, sB, 8);  ISSUE8CC(sB, hp);         // 24
          WAITV(16); MFMA8ZR(a0, sC, 16); ISSUE8CC(sC, hp + 256);   // 24
          WAITV(16); MFMA8ZR(a0, sA, 24); ISSUE8CC(sA, hp + 512);   // 24
          WAITV(16); MFMA8ZR(a1, sB, 32); ISSUE8CC(sB, hp + 768);   // 24
          WAITV(16); MFMA8ZR(a1, sC, 40);
          WAITV(8);  MFMA8ZR(a1, sA, 48);
          WAITV(0);  MFMA8ZR(a1, sB, 56);
          float hsh[4];
          #pragma unroll
          for (int e = 0; e < 4; ++e) hsh[e] = __shfl_xor(hreg[e], 8);
          #pragma unroll
          for (int e = 0; e < 4; ++e) {
            float pre = a0[e] + a1[e] + bias1;
            float sg = 1.f / (1.f + __expf(-pre));
            if (isz) zreg[e] = sg;
            else st_b16_llc(&rh1b[(w * 16 + q * 4 + e) * 1024 + n_own], f2b(sg * hsh[e]));
          }
        } else {
          const u16* rp = rh1b + aoff;
          ISSUE8CC(sA, rp);                          // 8
          ISSUE8CC(sB, rp + 256);                    // 16
          ISSUE8CC(sC, rp + 512);                    // 24
          WAITV(16); MFMA8G(a0, sA, 0);  ISSUE8CC(sA, rp + 768);    // 24
          WAITV(16); MFMA8G(a0, sB, 8);  ISSUE8CC(sB, hp);          // 24
          WAITV(16); MFMA8G(a0, sC, 16); ISSUE8CC(sC, hp + 256);    // 24
          WAITV(16); MFMA8G(a0, sA, 24); ISSUE8CC(sA, hp + 512);    // 24
          WAITV(16); MFMA8G(a1, sB, 32); ISSUE8CC(sB, hp + 768);    // 24
          WAITV(16); MFMA8G(a1, sC, 40);
          WAITV(8);  MFMA8G(a1, sA, 48);
          WAITV(0);  MFMA8G(a1, sB, 56);
          if (isz) {
            #pragma unroll
            for (int e = 0; e < 4; ++e) {
              int b = w * 16 + q * 4 + e;
              float pre = a0[e] + a1[e] + bias2;
              float ex = __expf(2.f * pre);
              float gv = 1.f - 2.f / (ex + 1.f);
              float hn = zreg[e] * hreg[e] + (1.f - zreg[e]) * gv;
              hreg[e] = hn;
              u16 hnb = f2b(hn);
              st_b16_llc(&hb1[b * 1024 + n_own], hnb);
              seq1[((size_t)b * 512 + s) * 1024 + n_own] = hnb;   // plain store
              if (s == 511) hid[1024 + b * 2048 + n_own] = hn;
            }
          }
        }
      }
    }
    // Last interval needs no barrier: kernel boundary orders seq1/hid for gemm_bt.
    if (p < 1025) wg_bar(slots, (u32)(p + 2), bid, tid, lane, w);
  }
}

// ---------------- host ----------------
extern "C" void kernel_launch(void* const* d_in, const int* in_sizes, int n_in,
                              void* d_out, int out_size, void* d_ws, size_t ws_size,
                              hipStream_t stream) {
  (void)in_sizes; (void)n_in; (void)out_size; (void)ws_size;
  char* ws = (char*)d_ws;
  const size_t MB = 1024ull * 1024ull;
  u16* seq1 = (u16*)(ws + 0);                         // 32 MB
  u16* xb   = (u16*)(ws + 32 * MB);                   // 4 MB
  u16* Wh0  = (u16*)(ws + 36 * MB);                   // 6 MB
  u16* Wh1  = (u16*)(ws + 42 * MB);                   // 6 MB
  u16* Wx0  = (u16*)(ws + 48 * MB);                   // 0.75 MB
  u16* Wx1  = (u16*)(ws + 49 * MB);                   // 6 MB
  u16* Wyb  = (u16*)(ws + 55 * MB);                   // 0.25 MB
  u16* h0buf = (u16*)(ws + 56 * MB);                  // 2 x 64 KB
  u16* hb1  = (u16*)(ws + 56 * MB + 128 * 1024);      // 64 KB
  u16* rh0b = (u16*)(ws + 56 * MB + 192 * 1024);      // 64 KB
  u16* rh1b = (u16*)(ws + 56 * MB + 256 * 1024);      // 64 KB
  u32* slots = (u32*)(ws + 56 * MB + 320 * 1024);     // 256 L1 + 8 gslots (2 KB)

  hipMemsetAsync(slots, 0, 2048, stream);

  auto cast = [&](const void* in, u16* out, int n) {
    cast_f32_bf16<<<(n + 255) / 256, 256, 0, stream>>>((const float*)in, out, n);
  };
  cast(d_in[0], xb, 2097152);                               // x
  cast(d_in[3],  Wh0 + 0,       1048576);                   // Whz0
  cast(d_in[6],  Wh0 + 1048576, 1048576);                   // Whr0
  cast(d_in[9],  Wh0 + 2097152, 1048576);                   // Whg0
  cast(d_in[12], Wh1 + 0,       1048576);                   // Whz1
  cast(d_in[15], Wh1 + 1048576, 1048576);                   // Whr1
  cast(d_in[18], Wh1 + 2097152, 1048576);                   // Whg1
  cast(d_in[2],  Wx0 + 0,      131072);                     // Wxz0
  cast(d_in[5],  Wx0 + 131072, 131072);                     // Wxr0
  cast(d_in[8],  Wx0 + 262144, 131072);                     // Wxg0
  cast(d_in[11], Wx1 + 0,       1048576);                   // Wxz1
  cast(d_in[14], Wx1 + 1048576, 1048576);                   // Wxr1
  cast(d_in[17], Wx1 + 2097152, 1048576);                   // Wxg1
  cast(d_in[20], Wyb, 131072);                              // Wy

  float* y_out = (float*)d_out;
  float* hid = y_out + 2097152;                             // hidden (32,2,1024)

  gru_pipe<<<256, dim3(128), 0, stream>>>(
      Wh0, Wx0, Wh1, Wx1,
      (const float*)d_in[4],  (const float*)d_in[7],  (const float*)d_in[10],
      (const float*)d_in[13], (const float*)d_in[16], (const float*)d_in[19],
      xb, (const float*)d_in[1],
      h0buf, hb1, rh0b, rh1b, seq1, hid, slots);

  // output projection y = seq1 @ Wy^T + by  (M=16384, N=128, K=1024)
  gemm_bt<<<dim3(128, 1), dim3(256), 0, stream>>>(
      seq1, Wyb, 16384, 128, 1024, (const float*)d_in[21], y_out);
}